// Round 5
// baseline (88.262 us; speedup 1.0000x reference)
//
#include <hip/hip_runtime.h>
#include <hip/hip_bf16.h>
#include <math.h>

#define BB 8
#define TT 2048
#define EE 1024
#define HH 64
// 1/sqrt(64) * log2(e): fold into q so scores are in exp2 domain
#define QSCALE 0.18033688011112042f
#define JPB 576            // split-K jobs per batch: sum_s (s/16 + 1)
#define NJOB (BB * JPB)    // 4608

typedef __attribute__((ext_vector_type(8))) short short8;
typedef __attribute__((ext_vector_type(4))) float f32x4;
typedef __attribute__((ext_vector_type(4))) unsigned short us4;

__device__ inline unsigned short f2bf(float f) {
  union { __hip_bfloat16 h; unsigned short u; } cv;
  cv.h = __float2bfloat16(f);
  return cv.u;
}

// ---------- prep: fragment-ordered weights --------------------------------
__global__ __launch_bounds__(256) void prep_w(
    const float* __restrict__ Wk, const float* __restrict__ Wq,
    const float* __restrict__ Wv, unsigned short* __restrict__ Wf) {
  const int idx = blockIdx.x * 256 + threadIdx.x;  // 12*32*64 = 24576
  const int lane = idx & 63, ks = (idx >> 6) & 31, t = idx >> 11;
  const int q = lane & 15, g = lane >> 4;
  const int m = t >> 2, h = (t & 3) * 16 + q;
  const float* W = (m == 0) ? Wk : (m == 1) ? Wq : Wv;
  const float sc = (m == 1) ? QSCALE : 1.f;
  const int e0 = ks * 32 + g * 8;
  unsigned short v[8];
  #pragma unroll
  for (int j = 0; j < 8; ++j) v[j] = f2bf(W[(e0 + j) * 64 + h] * sc);
  *(short8*)&Wf[(size_t)idx * 8] = *(short8*)v;
}

// ---------- QKV projection: barrier-free MFMA GEMM, depth-2 prefetch ------
__global__ __launch_bounds__(256) void qkv_proj(
    const float* __restrict__ x,
    const float* __restrict__ bk, const float* __restrict__ bq,
    const float* __restrict__ bv, const unsigned short* __restrict__ Wf,
    unsigned short* __restrict__ kb, unsigned short* __restrict__ qb,
    unsigned short* __restrict__ vt) {
  __shared__ alignas(16) unsigned short xs[16][1032];

  const int tid = threadIdx.x;
  const long row0 = (long)blockIdx.x * 16;
  const int w = tid >> 6, lane = tid & 63;
  const int q = lane & 15, g = lane >> 4;

  const float4* xg = (const float4*)&x[row0 * EE];
  #pragma unroll
  for (int i = 0; i < 16; ++i) {
    const int flat = i * 256 + tid;
    const int rr = flat >> 8, c4 = flat & 255;
    const float4 xv = xg[flat];
    us4 pk = {f2bf(xv.x), f2bf(xv.y), f2bf(xv.z), f2bf(xv.w)};
    *(us4*)&xs[rr][c4 * 4] = pk;
  }
  __syncthreads();

  const f32x4 z = {0.f, 0.f, 0.f, 0.f};
  f32x4 acc0 = z, acc1 = z, acc2 = z;
  const unsigned short* wf0 = &Wf[(size_t)w * 16384 + (size_t)lane * 8];

  short8 a0, a1, b00, b01, b02, b10, b11, b12;
  a0  = *(const short8*)&xs[q][g * 8];
  b00 = *(const short8*)&wf0[0];
  b01 = *(const short8*)&wf0[65536];
  b02 = *(const short8*)&wf0[131072];
  a1  = *(const short8*)&xs[q][32 + g * 8];
  b10 = *(const short8*)&wf0[512];
  b11 = *(const short8*)&wf0[65536 + 512];
  b12 = *(const short8*)&wf0[131072 + 512];

  #pragma unroll
  for (int ks = 0; ks < 32; ++ks) {
    if ((ks & 1) == 0) {
      acc0 = __builtin_amdgcn_mfma_f32_16x16x32_bf16(a0, b00, acc0, 0, 0, 0);
      acc1 = __builtin_amdgcn_mfma_f32_16x16x32_bf16(a0, b01, acc1, 0, 0, 0);
      acc2 = __builtin_amdgcn_mfma_f32_16x16x32_bf16(a0, b02, acc2, 0, 0, 0);
      if (ks + 2 < 32) {
        a0  = *(const short8*)&xs[q][(ks + 2) * 32 + g * 8];
        b00 = *(const short8*)&wf0[(ks + 2) * 512];
        b01 = *(const short8*)&wf0[65536 + (ks + 2) * 512];
        b02 = *(const short8*)&wf0[131072 + (ks + 2) * 512];
      }
    } else {
      acc0 = __builtin_amdgcn_mfma_f32_16x16x32_bf16(a1, b10, acc0, 0, 0, 0);
      acc1 = __builtin_amdgcn_mfma_f32_16x16x32_bf16(a1, b11, acc1, 0, 0, 0);
      acc2 = __builtin_amdgcn_mfma_f32_16x16x32_bf16(a1, b12, acc2, 0, 0, 0);
      if (ks + 2 < 32) {
        a1  = *(const short8*)&xs[q][(ks + 2) * 32 + g * 8];
        b10 = *(const short8*)&wf0[(ks + 2) * 512];
        b11 = *(const short8*)&wf0[65536 + (ks + 2) * 512];
        b12 = *(const short8*)&wf0[131072 + (ks + 2) * 512];
      }
    }
  }

  const int h = w * 16 + q;
  const float biask = bk[h], biasq = bq[h] * QSCALE, biasv = bv[h];
  #pragma unroll
  for (int r = 0; r < 4; ++r) {
    const long row = row0 + 4 * g + r;
    kb[row * 64 + h] = f2bf(acc0[r] + biask);
    qb[row * 64 + h] = f2bf(acc1[r] + biasq);
    const long bi = row >> 11, tl = row & 2047;
    vt[(bi * 64 + h) * TT + tl] = f2bf(acc2[r] + biasv);
  }
}

// ---------- attention, split-K partials: one wave per uniform job ----------
// job (b, strip s, chunk c): tiles [8c, min(8c+8, (s+2)>>1)) of 32 keys.
// S^T = mfma(K, Q); O^T = mfma(V^T, P^T). No barriers; partials to pbuf/mlp.
#define LOADK(K0, K1, K2, K3, KK0) do {                                     \
    const unsigned short* kp_ = kbase + (size_t)(KK0) * 64;                 \
    K0 = *(const short8*)&kp_[g * 8];                                       \
    K1 = *(const short8*)&kp_[32 + g * 8];                                  \
    K2 = *(const short8*)&kp_[16 * 64 + g * 8];                             \
    K3 = *(const short8*)&kp_[16 * 64 + 32 + g * 8];                        \
  } while (0)

#define BODY(KC0, KC1, KC2, KC3, KN0, KN1, KN2, KN3, tt, PREF) do {         \
    const int k0_ = (tt) * 32;                                              \
    const unsigned short* vp_ = vbase + k0_;                                \
    const short8 V0 = *(const short8*)&vp_[g * 8];                          \
    const short8 V1 = *(const short8*)&vp_[16 * TT + g * 8];                \
    const short8 V2 = *(const short8*)&vp_[32 * TT + g * 8];                \
    const short8 V3 = *(const short8*)&vp_[48 * TT + g * 8];                \
    if (PREF) LOADK(KN0, KN1, KN2, KN3, k0_ + 32);                          \
    f32x4 sa = __builtin_amdgcn_mfma_f32_16x16x32_bf16(KC0, Qf0, z, 0,0,0); \
    sa = __builtin_amdgcn_mfma_f32_16x16x32_bf16(KC1, Qf1, sa, 0,0,0);      \
    f32x4 sb = __builtin_amdgcn_mfma_f32_16x16x32_bf16(KC2, Qf0, z, 0,0,0); \
    sb = __builtin_amdgcn_mfma_f32_16x16x32_bf16(KC3, Qf1, sb, 0,0,0);      \
    if (k0_ + 31 > q0) {                                                    \
      _Pragma("unroll")                                                     \
      for (int r = 0; r < 4; ++r) {                                         \
        if (k0_ + 4 * g + r > qg) sa[r] = -INFINITY;                        \
        if (k0_ + 16 + 4 * g + r > qg) sb[r] = -INFINITY;                   \
      }                                                                     \
    }                                                                       \
    float tmax = fmaxf(fmaxf(fmaxf(sa[0], sa[1]), fmaxf(sa[2], sa[3])),     \
                       fmaxf(fmaxf(sb[0], sb[1]), fmaxf(sb[2], sb[3])));    \
    tmax = fmaxf(tmax, __shfl_xor(tmax, 16));                               \
    tmax = fmaxf(tmax, __shfl_xor(tmax, 32));                               \
    const float nm = fmaxf(m, tmax);                                        \
    const float rs = __builtin_amdgcn_exp2f(m - nm);                        \
    float ps = 0.f;                                                         \
    _Pragma("unroll")                                                       \
    for (int r = 0; r < 4; ++r) {                                           \
      sa[r] = __builtin_amdgcn_exp2f(sa[r] - nm); ps += sa[r];              \
      sb[r] = __builtin_amdgcn_exp2f(sb[r] - nm); ps += sb[r];              \
    }                                                                       \
    ps += __shfl_xor(ps, 16);                                               \
    ps += __shfl_xor(ps, 32);                                               \
    l = l * rs + ps;                                                        \
    m = nm;                                                                 \
    o0 *= rs; o1 *= rs; o2 *= rs; o3 *= rs;                                 \
    us4 plo = {f2bf(sa[0]), f2bf(sa[1]), f2bf(sa[2]), f2bf(sa[3])};         \
    us4 phi = {f2bf(sb[0]), f2bf(sb[1]), f2bf(sb[2]), f2bf(sb[3])};         \
    *(us4*)&PsT[w][q][4 * g] = plo;                                         \
    *(us4*)&PsT[w][q][16 + 4 * g] = phi;                                    \
    const short8 Pf = *(const short8*)&PsT[w][q][8 * g];                    \
    o0 = __builtin_amdgcn_mfma_f32_16x16x32_bf16(V0, Pf, o0, 0,0,0);        \
    o1 = __builtin_amdgcn_mfma_f32_16x16x32_bf16(V1, Pf, o1, 0,0,0);        \
    o2 = __builtin_amdgcn_mfma_f32_16x16x32_bf16(V2, Pf, o2, 0,0,0);        \
    o3 = __builtin_amdgcn_mfma_f32_16x16x32_bf16(V3, Pf, o3, 0,0,0);        \
  } while (0)

__global__ __launch_bounds__(256) void attn_part(
    const unsigned short* __restrict__ qb, const unsigned short* __restrict__ kb,
    const unsigned short* __restrict__ vt, float* __restrict__ pbuf,
    float* __restrict__ mlp) {
  __shared__ alignas(16) unsigned short PsT[4][16][36];

  const int tid = threadIdx.x;
  const int w = tid >> 6, lane = tid & 63;
  const int q = lane & 15, g = lane >> 4;

  const int b = blockIdx.x & 7;
  const int j = (blockIdx.x >> 3) * 4 + w;   // 0..575
  // decode j -> (strip s, chunk c): group a has 16 strips x (a+1) chunks
  int a = (int)((sqrtf((float)(4 + 2 * j)) - 2.f) * 0.25f);
  while (8 * (a + 1) * (a + 2) <= j) ++a;
  while (8 * a * (a + 1) > j) --a;
  const int rem = j - 8 * a * (a + 1);
  const int s = 16 * a + rem / (a + 1);
  const int c = rem % (a + 1);

  const int q0 = s * 16;
  const long base = (long)b * TT;
  const int nt = (s + 2) >> 1;
  int t = 8 * c;
  const int te = (8 * c + 8 < nt) ? (8 * c + 8) : nt;

  const unsigned short* kbase = &kb[(base + q) * 64];
  const unsigned short* vbase = &vt[((long)b * 64 + q) * TT];

  const short8 Qf0 = *(const short8*)&qb[(base + q0 + q) * 64 + g * 8];
  const short8 Qf1 = *(const short8*)&qb[(base + q0 + q) * 64 + 32 + g * 8];

  const f32x4 z = {0.f, 0.f, 0.f, 0.f};
  float m = -INFINITY, l = 0.f;
  f32x4 o0 = z, o1 = z, o2 = z, o3 = z;
  const int qg = q0 + q;

  short8 A0, A1, A2, A3, B0, B1, B2, B3;
  LOADK(A0, A1, A2, A3, t * 32);
  while (t + 1 < te) {
    BODY(A0, A1, A2, A3, B0, B1, B2, B3, t, 1); ++t;
    BODY(B0, B1, B2, B3, A0, A1, A2, A3, t, 1); ++t;
  }
  if (t < te) BODY(A0, A1, A2, A3, B0, B1, B2, B3, t, 0);

  // store partial: pbuf[J][row=h][q], ml replicated across g
  float* pp = pbuf + (size_t)(b * JPB + j) * 1024;
  #pragma unroll
  for (int hb = 0; hb < 4; ++hb) {
    const f32x4 oc = (hb == 0) ? o0 : (hb == 1) ? o1 : (hb == 2) ? o2 : o3;
    #pragma unroll
    for (int r = 0; r < 4; ++r) pp[(16 * hb + 4 * g + r) * 16 + q] = oc[r];
  }
  if (g == 0) {
    mlp[(size_t)(b * JPB + j) * 32 + q] = m;
    mlp[(size_t)(b * JPB + j) * 32 + 16 + q] = l;
  }
}

// ---------- merge split-K partials ----------------------------------------
__global__ __launch_bounds__(256) void attn_merge(
    const float* __restrict__ pbuf, const float* __restrict__ mlp,
    float* __restrict__ out) {
  const int b = blockIdx.x & 7, s = blockIdx.x >> 3;
  const int q0 = s * 16;
  const long base = (long)b * TT;
  const int nch = (s >> 4) + 1;
  const int a = s >> 4, r = s & 15;
  const int j0 = s + 8 * a * (a - 1) + r * a;     // cum(s)
  const size_t J0 = (size_t)b * JPB + j0;

  const int row = threadIdx.x & 63;
  const int qq = threadIdx.x >> 6;   // 0..3

  #pragma unroll
  for (int k = 0; k < 4; ++k) {
    const int q = qq + 4 * k;
    float M = -INFINITY;
    for (int i = 0; i < nch; ++i)
      M = fmaxf(M, mlp[(J0 + i) * 32 + q]);
    float fsum = 0.f, acc = 0.f;
    for (int i = 0; i < nch; ++i) {
      const float fi = __builtin_amdgcn_exp2f(mlp[(J0 + i) * 32 + q] - M);
      fsum += fi * mlp[(J0 + i) * 32 + 16 + q];
      acc  += fi * pbuf[(J0 + i) * 1024 + row * 16 + q];
    }
    out[(base + q0 + q) * 64 + row] = acc / fsum;
  }
}

extern "C" void kernel_launch(void* const* d_in, const int* in_sizes, int n_in,
                              void* d_out, int out_size, void* d_ws, size_t ws_size,
                              hipStream_t stream) {
  const float* x  = (const float*)d_in[0];
  const float* Wk = (const float*)d_in[1];
  const float* bk = (const float*)d_in[2];
  const float* Wq = (const float*)d_in[3];
  const float* bq = (const float*)d_in[4];
  const float* Wv = (const float*)d_in[5];
  const float* bv = (const float*)d_in[6];
  float* out = (float*)d_out;

  unsigned short* qbuf = (unsigned short*)d_ws;            // [B*T][64]
  unsigned short* kbuf = qbuf + (size_t)BB * TT * HH;      // [B*T][64]
  unsigned short* vtb  = kbuf + (size_t)BB * TT * HH;      // [B][64][T]
  unsigned short* Wf   = vtb + (size_t)BB * TT * HH;       // [12][32][64][8]
  float* pbuf = (float*)(Wf + 196608);                     // [NJOB][64][16]
  float* mlp  = pbuf + (size_t)NJOB * 1024;                // [NJOB][2][16]

  prep_w<<<dim3(96), 256, 0, stream>>>(Wk, Wq, Wv, Wf);
  qkv_proj<<<dim3(1024), 256, 0, stream>>>(x, bk, bq, bv, Wf, kbuf, qbuf, vtb);
  attn_part<<<dim3(8 * (JPB / 4)), 256, 0, stream>>>(qbuf, kbuf, vtb, pbuf, mlp);
  attn_merge<<<dim3(1024), 256, 0, stream>>>(pbuf, mlp, out);
}

// Round 6
// 70.362 us; speedup vs baseline: 1.2544x; 1.2544x over previous
//
#include <hip/hip_runtime.h>
#include <hip/hip_bf16.h>
#include <math.h>

#define BB 8
#define TT 2048
#define EE 1024
#define HH 64
// 1/sqrt(64) * log2(e): fold into q so scores are in exp2 domain
#define QSCALE 0.18033688011112042f

typedef __attribute__((ext_vector_type(8))) short short8;
typedef __attribute__((ext_vector_type(4))) float f32x4;
typedef __attribute__((ext_vector_type(4))) unsigned short us4;

__device__ inline unsigned short f2bf(float f) {
  union { __hip_bfloat16 h; unsigned short u; } cv;
  cv.h = __float2bfloat16(f);
  return cv.u;
}

// ---------- prep: fragment-ordered weights --------------------------------
// Wf[t][ks][lane][j], t = m*4+hb; h=(t&3)*16+(lane&15), e=ks*32+(lane>>4)*8+j
__global__ __launch_bounds__(256) void prep_w(
    const float* __restrict__ Wk, const float* __restrict__ Wq,
    const float* __restrict__ Wv, unsigned short* __restrict__ Wf) {
  const int idx = blockIdx.x * 256 + threadIdx.x;  // 12*32*64 = 24576
  const int lane = idx & 63, ks = (idx >> 6) & 31, t = idx >> 11;
  const int q = lane & 15, g = lane >> 4;
  const int m = t >> 2, h = (t & 3) * 16 + q;
  const float* W = (m == 0) ? Wk : (m == 1) ? Wq : Wv;
  const float sc = (m == 1) ? QSCALE : 1.f;
  const int e0 = ks * 32 + g * 8;
  unsigned short v[8];
  #pragma unroll
  for (int j = 0; j < 8; ++j) v[j] = f2bf(W[(e0 + j) * 64 + h] * sc);
  *(short8*)&Wf[(size_t)idx * 8] = *(short8*)v;
}

// ---------- QKV projection: 32 rows/block, wave = 2 M-strips x 3 N-tiles ---
__global__ __launch_bounds__(256) void qkv_proj(
    const float* __restrict__ x,
    const float* __restrict__ bk, const float* __restrict__ bq,
    const float* __restrict__ bv, const unsigned short* __restrict__ Wf,
    unsigned short* __restrict__ kb, unsigned short* __restrict__ qb,
    unsigned short* __restrict__ vt) {
  __shared__ alignas(16) unsigned short xs[32][1032];

  const int tid = threadIdx.x;
  const long row0 = (long)blockIdx.x * 32;
  const int w = tid >> 6, lane = tid & 63;
  const int q = lane & 15, g = lane >> 4;

  // stage 32x1024 fp32 -> bf16 (coalesced float4)
  const float4* xg = (const float4*)&x[row0 * EE];
  #pragma unroll
  for (int i = 0; i < 32; ++i) {
    const int flat = i * 256 + tid;           // 0..8191
    const int rr = flat >> 8, c4 = flat & 255;
    const float4 xv = xg[flat];
    us4 pk = {f2bf(xv.x), f2bf(xv.y), f2bf(xv.z), f2bf(xv.w)};
    *(us4*)&xs[rr][c4 * 4] = pk;
  }
  __syncthreads();

  const f32x4 z = {0.f, 0.f, 0.f, 0.f};
  f32x4 acc00 = z, acc01 = z, acc02 = z;   // strip 0 x 3 tiles
  f32x4 acc10 = z, acc11 = z, acc12 = z;   // strip 1 x 3 tiles
  const unsigned short* wf0 = &Wf[(size_t)(3 * w) * 16384 + (size_t)lane * 8];

  short8 a0A, a1A, b0A, b1A, b2A, a0B, a1B, b0B, b1B, b2B;
  a0A = *(const short8*)&xs[q][g * 8];
  a1A = *(const short8*)&xs[16 + q][g * 8];
  b0A = *(const short8*)&wf0[0];
  b1A = *(const short8*)&wf0[16384];
  b2A = *(const short8*)&wf0[32768];
  a0B = *(const short8*)&xs[q][32 + g * 8];
  a1B = *(const short8*)&xs[16 + q][32 + g * 8];
  b0B = *(const short8*)&wf0[512];
  b1B = *(const short8*)&wf0[16384 + 512];
  b2B = *(const short8*)&wf0[32768 + 512];

  #pragma unroll
  for (int ks = 0; ks < 32; ++ks) {
    if ((ks & 1) == 0) {
      acc00 = __builtin_amdgcn_mfma_f32_16x16x32_bf16(a0A, b0A, acc00, 0, 0, 0);
      acc01 = __builtin_amdgcn_mfma_f32_16x16x32_bf16(a0A, b1A, acc01, 0, 0, 0);
      acc02 = __builtin_amdgcn_mfma_f32_16x16x32_bf16(a0A, b2A, acc02, 0, 0, 0);
      acc10 = __builtin_amdgcn_mfma_f32_16x16x32_bf16(a1A, b0A, acc10, 0, 0, 0);
      acc11 = __builtin_amdgcn_mfma_f32_16x16x32_bf16(a1A, b1A, acc11, 0, 0, 0);
      acc12 = __builtin_amdgcn_mfma_f32_16x16x32_bf16(a1A, b2A, acc12, 0, 0, 0);
      if (ks + 2 < 32) {
        a0A = *(const short8*)&xs[q][(ks + 2) * 32 + g * 8];
        a1A = *(const short8*)&xs[16 + q][(ks + 2) * 32 + g * 8];
        b0A = *(const short8*)&wf0[(ks + 2) * 512];
        b1A = *(const short8*)&wf0[16384 + (ks + 2) * 512];
        b2A = *(const short8*)&wf0[32768 + (ks + 2) * 512];
      }
    } else {
      acc00 = __builtin_amdgcn_mfma_f32_16x16x32_bf16(a0B, b0B, acc00, 0, 0, 0);
      acc01 = __builtin_amdgcn_mfma_f32_16x16x32_bf16(a0B, b1B, acc01, 0, 0, 0);
      acc02 = __builtin_amdgcn_mfma_f32_16x16x32_bf16(a0B, b2B, acc02, 0, 0, 0);
      acc10 = __builtin_amdgcn_mfma_f32_16x16x32_bf16(a1B, b0B, acc10, 0, 0, 0);
      acc11 = __builtin_amdgcn_mfma_f32_16x16x32_bf16(a1B, b1B, acc11, 0, 0, 0);
      acc12 = __builtin_amdgcn_mfma_f32_16x16x32_bf16(a1B, b2B, acc12, 0, 0, 0);
      if (ks + 2 < 32) {
        a0B = *(const short8*)&xs[q][(ks + 2) * 32 + g * 8];
        a1B = *(const short8*)&xs[16 + q][(ks + 2) * 32 + g * 8];
        b0B = *(const short8*)&wf0[(ks + 2) * 512];
        b1B = *(const short8*)&wf0[16384 + (ks + 2) * 512];
        b2B = *(const short8*)&wf0[32768 + (ks + 2) * 512];
      }
    }
  }

  // epilogue: wave w owns global tiles {3w,3w+1,3w+2}; D[4g+r][q] per strip
  #pragma unroll
  for (int i = 0; i < 3; ++i) {
    const int tgl = 3 * w + i;
    const int m = tgl >> 2, hb = tgl & 3;
    const int h = hb * 16 + q;
    const float bias = (m == 0) ? bk[h] : (m == 1) ? bq[h] * QSCALE : bv[h];
    #pragma unroll
    for (int st = 0; st < 2; ++st) {
      const f32x4 a = (st == 0) ? ((i == 0) ? acc00 : (i == 1) ? acc01 : acc02)
                                : ((i == 0) ? acc10 : (i == 1) ? acc11 : acc12);
      #pragma unroll
      for (int r = 0; r < 4; ++r) {
        const long row = row0 + st * 16 + 4 * g + r;
        const unsigned short ov = f2bf(a[r] + bias);
        if (m == 0) kb[row * 64 + h] = ov;
        else if (m == 1) qb[row * 64 + h] = ov;
        else {
          const long bi = row >> 11, tl = row & 2047;
          vt[(bi * 64 + h) * TT + tl] = ov;
        }
      }
    }
  }
}

// ---------- flash attention: block=(b,strip), 4 waves round-robin tiles ----
#define LOADK(K0, K1, K2, K3, KK0) do {                                     \
    const unsigned short* kp_ = kbase + (size_t)(KK0) * 64;                 \
    K0 = *(const short8*)&kp_[g * 8];                                       \
    K1 = *(const short8*)&kp_[32 + g * 8];                                  \
    K2 = *(const short8*)&kp_[16 * 64 + g * 8];                             \
    K3 = *(const short8*)&kp_[16 * 64 + 32 + g * 8];                        \
  } while (0)

#define BODY(KC0, KC1, KC2, KC3, KN0, KN1, KN2, KN3, tt, PREF) do {         \
    const int k0_ = (tt) * 32;                                              \
    const unsigned short* vp_ = vbase + k0_;                                \
    const short8 V0 = *(const short8*)&vp_[g * 8];                          \
    const short8 V1 = *(const short8*)&vp_[16 * TT + g * 8];                \
    const short8 V2 = *(const short8*)&vp_[32 * TT + g * 8];                \
    const short8 V3 = *(const short8*)&vp_[48 * TT + g * 8];                \
    if (PREF) LOADK(KN0, KN1, KN2, KN3, k0_ + 128);                         \
    f32x4 sa = __builtin_amdgcn_mfma_f32_16x16x32_bf16(KC0, Qf0, z, 0,0,0); \
    sa = __builtin_amdgcn_mfma_f32_16x16x32_bf16(KC1, Qf1, sa, 0,0,0);      \
    f32x4 sb = __builtin_amdgcn_mfma_f32_16x16x32_bf16(KC2, Qf0, z, 0,0,0); \
    sb = __builtin_amdgcn_mfma_f32_16x16x32_bf16(KC3, Qf1, sb, 0,0,0);      \
    if (k0_ + 31 > q0) {                                                    \
      _Pragma("unroll")                                                     \
      for (int r = 0; r < 4; ++r) {                                         \
        if (k0_ + 4 * g + r > qg) sa[r] = -INFINITY;                        \
        if (k0_ + 16 + 4 * g + r > qg) sb[r] = -INFINITY;                   \
      }                                                                     \
    }                                                                       \
    float tmax = fmaxf(fmaxf(fmaxf(sa[0], sa[1]), fmaxf(sa[2], sa[3])),     \
                       fmaxf(fmaxf(sb[0], sb[1]), fmaxf(sb[2], sb[3])));    \
    tmax = fmaxf(tmax, __shfl_xor(tmax, 16));                               \
    tmax = fmaxf(tmax, __shfl_xor(tmax, 32));                               \
    const float nm = fmaxf(m, tmax);                                        \
    const float rs = __builtin_amdgcn_exp2f(m - nm);                        \
    float ps = 0.f;                                                         \
    _Pragma("unroll")                                                       \
    for (int r = 0; r < 4; ++r) {                                           \
      sa[r] = __builtin_amdgcn_exp2f(sa[r] - nm); ps += sa[r];              \
      sb[r] = __builtin_amdgcn_exp2f(sb[r] - nm); ps += sb[r];              \
    }                                                                       \
    ps += __shfl_xor(ps, 16);                                               \
    ps += __shfl_xor(ps, 32);                                               \
    l = l * rs + ps;                                                        \
    m = nm;                                                                 \
    o0 *= rs; o1 *= rs; o2 *= rs; o3 *= rs;                                 \
    unsigned pw0, pw1, pw2, pw3;                                            \
    asm("v_cvt_pk_bf16_f32 %0, %1, %2" : "=v"(pw0) : "v"(sa[0]), "v"(sa[1]));\
    asm("v_cvt_pk_bf16_f32 %0, %1, %2" : "=v"(pw1) : "v"(sa[2]), "v"(sa[3]));\
    asm("v_cvt_pk_bf16_f32 %0, %1, %2" : "=v"(pw2) : "v"(sb[0]), "v"(sb[1]));\
    asm("v_cvt_pk_bf16_f32 %0, %1, %2" : "=v"(pw3) : "v"(sb[2]), "v"(sb[3]));\
    const int srcA = q + ((g & 1) << 5);                                    \
    const int srcB = srcA + 16;                                             \
    const unsigned r0a = __shfl((int)pw0, srcA);                            \
    const unsigned r1a = __shfl((int)pw1, srcA);                            \
    const unsigned r2a = __shfl((int)pw2, srcA);                            \
    const unsigned r3a = __shfl((int)pw3, srcA);                            \
    const unsigned r0b = __shfl((int)pw0, srcB);                            \
    const unsigned r1b = __shfl((int)pw1, srcB);                            \
    const unsigned r2b = __shfl((int)pw2, srcB);                            \
    const unsigned r3b = __shfl((int)pw3, srcB);                            \
    union { unsigned u[4]; short8 s; } pf_;                                 \
    const bool hi_ = (g >= 2);                                              \
    pf_.u[0] = hi_ ? r2a : r0a;                                             \
    pf_.u[1] = hi_ ? r3a : r1a;                                             \
    pf_.u[2] = hi_ ? r2b : r0b;                                             \
    pf_.u[3] = hi_ ? r3b : r1b;                                             \
    const short8 Pf = pf_.s;                                                \
    o0 = __builtin_amdgcn_mfma_f32_16x16x32_bf16(V0, Pf, o0, 0,0,0);        \
    o1 = __builtin_amdgcn_mfma_f32_16x16x32_bf16(V1, Pf, o1, 0,0,0);        \
    o2 = __builtin_amdgcn_mfma_f32_16x16x32_bf16(V2, Pf, o2, 0,0,0);        \
    o3 = __builtin_amdgcn_mfma_f32_16x16x32_bf16(V3, Pf, o3, 0,0,0);        \
  } while (0)

__global__ __launch_bounds__(256) void attn_fwd(
    const unsigned short* __restrict__ qb, const unsigned short* __restrict__ kb,
    const unsigned short* __restrict__ vt, float* __restrict__ out) {
  __shared__ float accS[4][64][17];
  __shared__ float mlS[4][2][16];

  const int tid = threadIdx.x;
  const int w = tid >> 6, lane = tid & 63;
  const int q = lane & 15, g = lane >> 4;

  const int b = blockIdx.x & 7;
  const int s = blockIdx.x >> 3;     // strip 0..127
  const int q0 = s * 16;
  const long base = (long)b * TT;
  const int nt = (s + 2) >> 1;

  const unsigned short* kbase = &kb[(base + q) * 64];
  const unsigned short* vbase = &vt[((long)b * 64 + q) * TT];

  const short8 Qf0 = *(const short8*)&qb[(base + q0 + q) * 64 + g * 8];
  const short8 Qf1 = *(const short8*)&qb[(base + q0 + q) * 64 + 32 + g * 8];

  const f32x4 z = {0.f, 0.f, 0.f, 0.f};
  float m = -INFINITY, l = 0.f;
  f32x4 o0 = z, o1 = z, o2 = z, o3 = z;
  const int qg = q0 + q;

  int t = w;
  if (t < nt) {
    short8 A0, A1, A2, A3, B0, B1, B2, B3;
    LOADK(A0, A1, A2, A3, t * 32);
    while (t + 8 < nt) {
      BODY(A0, A1, A2, A3, B0, B1, B2, B3, t, 1);
      BODY(B0, B1, B2, B3, A0, A1, A2, A3, t + 4, 1);
      t += 8;
    }
    if (t + 4 < nt) {
      BODY(A0, A1, A2, A3, B0, B1, B2, B3, t, 1);
      BODY(B0, B1, B2, B3, A0, A1, A2, A3, t + 4, 0);
    } else {
      BODY(A0, A1, A2, A3, B0, B1, B2, B3, t, 0);
    }
  }

  // write per-wave state
  #pragma unroll
  for (int hb = 0; hb < 4; ++hb) {
    const f32x4 a = (hb == 0) ? o0 : (hb == 1) ? o1 : (hb == 2) ? o2 : o3;
    #pragma unroll
    for (int r = 0; r < 4; ++r) accS[w][16 * hb + 4 * g + r][q] = a[r];
  }
  if (g == 0) { mlS[w][0][q] = m; mlS[w][1][q] = l; }
  __syncthreads();

  // parallel merge: thread -> (row = tid&63, q = (tid>>6) + 4k)
  const int row = tid & 63, qq = tid >> 6;
  #pragma unroll
  for (int k = 0; k < 4; ++k) {
    const int qv = qq + 4 * k;
    const float m0 = mlS[0][0][qv], m1 = mlS[1][0][qv];
    const float m2 = mlS[2][0][qv], m3 = mlS[3][0][qv];
    const float M = fmaxf(fmaxf(m0, m1), fmaxf(m2, m3));
    const float f0 = __builtin_amdgcn_exp2f(m0 - M);
    const float f1 = __builtin_amdgcn_exp2f(m1 - M);
    const float f2 = __builtin_amdgcn_exp2f(m2 - M);
    const float f3 = __builtin_amdgcn_exp2f(m3 - M);
    const float L = f0 * mlS[0][1][qv] + f1 * mlS[1][1][qv] +
                    f2 * mlS[2][1][qv] + f3 * mlS[3][1][qv];
    const float acc = f0 * accS[0][row][qv] + f1 * accS[1][row][qv] +
                      f2 * accS[2][row][qv] + f3 * accS[3][row][qv];
    out[(base + q0 + qv) * 64 + row] = acc / L;
  }
}

extern "C" void kernel_launch(void* const* d_in, const int* in_sizes, int n_in,
                              void* d_out, int out_size, void* d_ws, size_t ws_size,
                              hipStream_t stream) {
  const float* x  = (const float*)d_in[0];
  const float* Wk = (const float*)d_in[1];
  const float* bk = (const float*)d_in[2];
  const float* Wq = (const float*)d_in[3];
  const float* bq = (const float*)d_in[4];
  const float* Wv = (const float*)d_in[5];
  const float* bv = (const float*)d_in[6];
  float* out = (float*)d_out;

  unsigned short* qbuf = (unsigned short*)d_ws;            // [B*T][64]
  unsigned short* kbuf = qbuf + (size_t)BB * TT * HH;      // [B*T][64]
  unsigned short* vtb  = kbuf + (size_t)BB * TT * HH;      // [B][64][T]
  unsigned short* Wf   = vtb + (size_t)BB * TT * HH;       // [12][32][64][8]

  prep_w<<<dim3(96), 256, 0, stream>>>(Wk, Wq, Wv, Wf);
  qkv_proj<<<dim3(512), 256, 0, stream>>>(x, bk, bq, bv, Wf, kbuf, qbuf, vtb);
  attn_fwd<<<dim3(1024), 256, 0, stream>>>(qbuf, kbuf, vtb, out);
}

// Round 8
// 50.823 us; speedup vs baseline: 1.7367x; 1.3845x over previous
//
#include <hip/hip_runtime.h>
#include <hip/hip_bf16.h>
#include <math.h>

#define BB 8
#define TT 2048
#define EE 1024
#define HH 64
// 1/sqrt(64) * log2(e): fold into q so scores are in exp2 domain
#define QSCALE 0.18033688011112042f

typedef __attribute__((ext_vector_type(8))) short short8;
typedef __attribute__((ext_vector_type(4))) float f32x4;
typedef __attribute__((ext_vector_type(4))) unsigned short us4;

__device__ inline unsigned short f2bf(float f) {
  union { __hip_bfloat16 h; unsigned short u; } cv;
  cv.h = __float2bfloat16(f);
  return cv.u;
}

// ---------- prep: fragment-ordered weights --------------------------------
// Wf[t][ks][lane][j], t = m*4+hb; h=(t&3)*16+(lane&15), e=ks*32+(lane>>4)*8+j
__global__ __launch_bounds__(256) void prep_w(
    const float* __restrict__ Wk, const float* __restrict__ Wq,
    const float* __restrict__ Wv, unsigned short* __restrict__ Wf) {
  const int idx = blockIdx.x * 256 + threadIdx.x;  // 12*32*64 = 24576
  const int lane = idx & 63, ks = (idx >> 6) & 31, t = idx >> 11;
  const int q = lane & 15, g = lane >> 4;
  const int m = t >> 2, h = (t & 3) * 16 + q;
  const float* W = (m == 0) ? Wk : (m == 1) ? Wq : Wv;
  const float sc = (m == 1) ? QSCALE : 1.f;
  const int e0 = ks * 32 + g * 8;
  unsigned short v[8];
  #pragma unroll
  for (int j = 0; j < 8; ++j) v[j] = f2bf(W[(e0 + j) * 64 + h] * sc);
  *(short8*)&Wf[(size_t)idx * 8] = *(short8*)v;
}

// ---------- QKV projection: 16 rows/block, chunked double-buffered staging -
// outputs fragment-packed: kf/qf[b][t16][half][lane][8], vf[b][t32][hq][lane][8]
__global__ __launch_bounds__(256) void qkv_proj(
    const float* __restrict__ x,
    const float* __restrict__ bk, const float* __restrict__ bq,
    const float* __restrict__ bv, const unsigned short* __restrict__ Wf,
    unsigned short* __restrict__ kf, unsigned short* __restrict__ qf,
    unsigned short* __restrict__ vf) {
  __shared__ alignas(16) unsigned short xs[2][16][264];

  const int tid = threadIdx.x;
  const long row0 = (long)blockIdx.x * 16;
  const int w = tid >> 6, lane = tid & 63;
  const int q = lane & 15, g = lane >> 4;

  const float4* xg = (const float4*)&x[row0 * EE];  // 16 rows x 256 f4

  // stage chunk 0 (cols 0..255)
  #pragma unroll
  for (int i = 0; i < 4; ++i) {
    const int flat = i * 256 + tid;
    const int rr = flat >> 6, c4 = flat & 63;
    const float4 xv = xg[rr * 256 + c4];
    us4 pk = {f2bf(xv.x), f2bf(xv.y), f2bf(xv.z), f2bf(xv.w)};
    *(us4*)&xs[0][rr][c4 * 4] = pk;
  }
  __syncthreads();

  const f32x4 z = {0.f, 0.f, 0.f, 0.f};
  f32x4 acc0 = z, acc1 = z, acc2 = z;
  const unsigned short* wf0 = &Wf[(size_t)w * 16384 + (size_t)lane * 8];

  float4 st[4];
  #pragma unroll
  for (int cc = 0; cc < 4; ++cc) {
    if (cc < 3) {  // issue next chunk's loads early (latency hides under MFMA)
      #pragma unroll
      for (int i = 0; i < 4; ++i) {
        const int flat = i * 256 + tid;
        const int rr = flat >> 6, c4 = flat & 63;
        st[i] = xg[rr * 256 + (cc + 1) * 64 + c4];
      }
    }
    #pragma unroll
    for (int ksl = 0; ksl < 8; ++ksl) {
      const short8 af = *(const short8*)&xs[cc & 1][q][ksl * 32 + g * 8];
      const int ks = cc * 8 + ksl;
      const short8 b0 = *(const short8*)&wf0[ks * 512];
      const short8 b1 = *(const short8*)&wf0[65536 + ks * 512];
      const short8 b2 = *(const short8*)&wf0[131072 + ks * 512];
      acc0 = __builtin_amdgcn_mfma_f32_16x16x32_bf16(af, b0, acc0, 0, 0, 0);
      acc1 = __builtin_amdgcn_mfma_f32_16x16x32_bf16(af, b1, acc1, 0, 0, 0);
      acc2 = __builtin_amdgcn_mfma_f32_16x16x32_bf16(af, b2, acc2, 0, 0, 0);
    }
    if (cc < 3) {
      #pragma unroll
      for (int i = 0; i < 4; ++i) {
        const int flat = i * 256 + tid;
        const int rr = flat >> 6, c4 = flat & 63;
        us4 pk = {f2bf(st[i].x), f2bf(st[i].y), f2bf(st[i].z), f2bf(st[i].w)};
        *(us4*)&xs[(cc + 1) & 1][rr][c4 * 4] = pk;
      }
    }
    __syncthreads();
  }

  // epilogue: D[row=4g+r][col=q], h = w*16+q; fragment-packed stores
  const int h = w * 16 + q;
  const float biask = bk[h], biasq = bq[h] * QSCALE, biasv = bv[h];
  const long bidx = row0 >> 11;
  const int tl0 = (int)(row0 & 2047);
  const int halfh = h >> 5, g2 = (h & 31) >> 3, jj = h & 7;
  const size_t kqbase = (size_t)bidx * 131072 + (size_t)(tl0 >> 4) * 1024 +
                        (size_t)halfh * 512 + (size_t)g2 * 128 + jj;
  #pragma unroll
  for (int r = 0; r < 4; ++r) {
    const int kq = 4 * g + r;
    kf[kqbase + kq * 8] = f2bf(acc0[r] + biask);
    qf[kqbase + kq * 8] = f2bf(acc1[r] + biasq);
    const int tl = tl0 + 4 * g + r;
    // vf[b][t32][hq][lane][8]: tile stride 2048 (was 1024 -- R7 bug)
    const size_t vidx = (size_t)bidx * 131072 + (size_t)(tl >> 5) * 2048 +
                        (size_t)(h >> 4) * 512 + (size_t)((tl & 31) >> 3) * 128 +
                        (size_t)(h & 15) * 8 + (tl & 7);
    vf[vidx] = f2bf(acc2[r] + biasv);
  }
}

// ---------- flash attention: paired strips, proportional wave split --------
// S^T = mfma(K, Q): lane holds S^T[key=4g+r][q]; defer-max online softmax;
// O^T = mfma(V^T, P^T). All operand loads coalesced (fragment-packed).
#define BODY(KC0, KC1, KC2, KC3, KN0, KN1, KN2, KN3, tt, PREF) do {          \
    const unsigned short* vp_ = vfb + (size_t)(tt) * 2048;                   \
    const short8 V0 = *(const short8*)&vp_[0];                               \
    const short8 V1 = *(const short8*)&vp_[512];                             \
    const short8 V2 = *(const short8*)&vp_[1024];                            \
    const short8 V3 = *(const short8*)&vp_[1536];                            \
    if (PREF) {                                                              \
      const unsigned short* kp_ = kfb + (size_t)((tt) + stride) * 2048;      \
      KN0 = *(const short8*)&kp_[0];                                         \
      KN1 = *(const short8*)&kp_[512];                                       \
      KN2 = *(const short8*)&kp_[1024];                                      \
      KN3 = *(const short8*)&kp_[1536];                                      \
    }                                                                        \
    f32x4 sa = __builtin_amdgcn_mfma_f32_16x16x32_bf16(KC0, Qf0, z, 0,0,0);  \
    sa = __builtin_amdgcn_mfma_f32_16x16x32_bf16(KC1, Qf1, sa, 0,0,0);       \
    f32x4 sb = __builtin_amdgcn_mfma_f32_16x16x32_bf16(KC2, Qf0, z, 0,0,0);  \
    sb = __builtin_amdgcn_mfma_f32_16x16x32_bf16(KC3, Qf1, sb, 0,0,0);       \
    const int k0_ = (tt) * 32;                                               \
    if (k0_ + 31 > q0) {                                                     \
      _Pragma("unroll")                                                      \
      for (int r = 0; r < 4; ++r) {                                          \
        if (k0_ + 4 * g + r > qg) sa[r] = -INFINITY;                         \
        if (k0_ + 16 + 4 * g + r > qg) sb[r] = -INFINITY;                    \
      }                                                                      \
    }                                                                        \
    float pmax = fmaxf(fmaxf(fmaxf(sa[0], sa[1]), fmaxf(sa[2], sa[3])),      \
                       fmaxf(fmaxf(sb[0], sb[1]), fmaxf(sb[2], sb[3])));     \
    if (!__all(pmax <= m + 8.0f)) {                                          \
      float tmax = pmax;                                                     \
      tmax = fmaxf(tmax, __shfl_xor(tmax, 16));                              \
      tmax = fmaxf(tmax, __shfl_xor(tmax, 32));                              \
      const float nm = fmaxf(m, tmax);                                       \
      const float rs = __builtin_amdgcn_exp2f(m - nm);                       \
      l *= rs; o0 *= rs; o1 *= rs; o2 *= rs; o3 *= rs;                       \
      m = nm;                                                                \
    }                                                                        \
    float ps = 0.f;                                                          \
    _Pragma("unroll")                                                        \
    for (int r = 0; r < 4; ++r) {                                            \
      sa[r] = __builtin_amdgcn_exp2f(sa[r] - m); ps += sa[r];                \
      sb[r] = __builtin_amdgcn_exp2f(sb[r] - m); ps += sb[r];                \
    }                                                                        \
    l += ps;                                                                 \
    unsigned pw0, pw1, pw2, pw3;                                             \
    asm("v_cvt_pk_bf16_f32 %0, %1, %2" : "=v"(pw0) : "v"(sa[0]), "v"(sa[1]));\
    asm("v_cvt_pk_bf16_f32 %0, %1, %2" : "=v"(pw1) : "v"(sa[2]), "v"(sa[3]));\
    asm("v_cvt_pk_bf16_f32 %0, %1, %2" : "=v"(pw2) : "v"(sb[0]), "v"(sb[1]));\
    asm("v_cvt_pk_bf16_f32 %0, %1, %2" : "=v"(pw3) : "v"(sb[2]), "v"(sb[3]));\
    const int srcA = q + ((g & 1) << 5);                                     \
    const int srcB = srcA + 16;                                              \
    const unsigned r0a = __shfl((int)pw0, srcA);                             \
    const unsigned r1a = __shfl((int)pw1, srcA);                             \
    const unsigned r2a = __shfl((int)pw2, srcA);                             \
    const unsigned r3a = __shfl((int)pw3, srcA);                             \
    const unsigned r0b = __shfl((int)pw0, srcB);                             \
    const unsigned r1b = __shfl((int)pw1, srcB);                             \
    const unsigned r2b = __shfl((int)pw2, srcB);                             \
    const unsigned r3b = __shfl((int)pw3, srcB);                             \
    union { unsigned u[4]; short8 s; } pf_;                                  \
    const bool hi_ = (g >= 2);                                               \
    pf_.u[0] = hi_ ? r2a : r0a;                                              \
    pf_.u[1] = hi_ ? r3a : r1a;                                              \
    pf_.u[2] = hi_ ? r2b : r0b;                                              \
    pf_.u[3] = hi_ ? r3b : r1b;                                              \
    const short8 Pf = pf_.s;                                                 \
    o0 = __builtin_amdgcn_mfma_f32_16x16x32_bf16(V0, Pf, o0, 0,0,0);         \
    o1 = __builtin_amdgcn_mfma_f32_16x16x32_bf16(V1, Pf, o1, 0,0,0);         \
    o2 = __builtin_amdgcn_mfma_f32_16x16x32_bf16(V2, Pf, o2, 0,0,0);         \
    o3 = __builtin_amdgcn_mfma_f32_16x16x32_bf16(V3, Pf, o3, 0,0,0);         \
  } while (0)

__global__ __launch_bounds__(512) void attn_fwd(
    const unsigned short* __restrict__ qf, const unsigned short* __restrict__ kf,
    const unsigned short* __restrict__ vf, float* __restrict__ out) {
  __shared__ float accS[8][64][17];
  __shared__ float mlS[8][2][16];

  const int tid = threadIdx.x;
  const int w = tid >> 6, lane = tid & 63;
  const int q = lane & 15, g = lane >> 4;

  const int b = blockIdx.x & 7;
  const int p = blockIdx.x >> 3;           // pair 0..63
  const int s1 = 127 - p;
  const int nt0 = (p + 2) >> 1, nt1 = (129 - p) >> 1;   // nt0 + nt1 = 65
  int k = (8 * nt0 + 32) / 65;
  if (k < 1) k = 1;
  if (k > 7) k = 7;

  const bool onS0 = (w < k);
  const int s = onS0 ? p : s1;
  const int nt = onS0 ? nt0 : nt1;
  const int stride = onS0 ? k : (8 - k);
  int t = onS0 ? w : (w - k);

  const int q0 = s * 16;
  const int qg = q0 + q;

  const unsigned short* kfb = kf + (size_t)b * 131072 + (size_t)lane * 8;
  const unsigned short* vfb = vf + (size_t)b * 131072 + (size_t)lane * 8;
  const unsigned short* qfb = qf + (size_t)b * 131072 + (size_t)s * 1024 +
                              (size_t)lane * 8;
  const short8 Qf0 = *(const short8*)&qfb[0];
  const short8 Qf1 = *(const short8*)&qfb[512];

  const f32x4 z = {0.f, 0.f, 0.f, 0.f};
  float m = -3.0e38f, l = 0.f;
  f32x4 o0 = z, o1 = z, o2 = z, o3 = z;

  {
    short8 A0, A1, A2, A3, B0, B1, B2, B3;
    const unsigned short* kp0 = kfb + (size_t)t * 2048;
    A0 = *(const short8*)&kp0[0];
    A1 = *(const short8*)&kp0[512];
    A2 = *(const short8*)&kp0[1024];
    A3 = *(const short8*)&kp0[1536];
    for (;;) {
      bool pf = (t + stride) < nt;
      BODY(A0, A1, A2, A3, B0, B1, B2, B3, t, pf);
      if (!pf) break;
      t += stride;
      pf = (t + stride) < nt;
      BODY(B0, B1, B2, B3, A0, A1, A2, A3, t, pf);
      if (!pf) break;
      t += stride;
    }
  }

  // finalize per-wave state: l summed across g (2 shfl, once per kernel)
  float lq = l;
  lq += __shfl_xor(lq, 16);
  lq += __shfl_xor(lq, 32);
  #pragma unroll
  for (int hb = 0; hb < 4; ++hb) {
    const f32x4 a = (hb == 0) ? o0 : (hb == 1) ? o1 : (hb == 2) ? o2 : o3;
    #pragma unroll
    for (int r = 0; r < 4; ++r) accS[w][16 * hb + 4 * g + r][q] = a[r];
  }
  if (g == 0) { mlS[w][0][q] = m; mlS[w][1][q] = lq; }
  __syncthreads();

  // merge: tid<256 -> strip p (slots 0..k-1), tid>=256 -> strip 127-p (k..7)
  const int half = tid >> 8;
  const int sm = half ? s1 : p;
  const int lo = half ? k : 0, hi = half ? 8 : k;
  const int row = tid & 63, qq = (tid >> 6) & 3;
  const long obase = ((long)b * TT + sm * 16) * 64;
  #pragma unroll
  for (int kk = 0; kk < 4; ++kk) {
    const int qv = qq + 4 * kk;
    float M = -INFINITY;
    for (int i = lo; i < hi; ++i) M = fmaxf(M, mlS[i][0][qv]);
    float L = 0.f, acc = 0.f;
    for (int i = lo; i < hi; ++i) {
      const float fi = __builtin_amdgcn_exp2f(mlS[i][0][qv] - M);
      L += fi * mlS[i][1][qv];
      acc += fi * accS[i][row][qv];
    }
    out[obase + (long)qv * 64 + row] = acc / L;
  }
}

extern "C" void kernel_launch(void* const* d_in, const int* in_sizes, int n_in,
                              void* d_out, int out_size, void* d_ws, size_t ws_size,
                              hipStream_t stream) {
  const float* x  = (const float*)d_in[0];
  const float* Wk = (const float*)d_in[1];
  const float* bk = (const float*)d_in[2];
  const float* Wq = (const float*)d_in[3];
  const float* bq = (const float*)d_in[4];
  const float* Wv = (const float*)d_in[5];
  const float* bv = (const float*)d_in[6];
  float* out = (float*)d_out;

  unsigned short* qfb = (unsigned short*)d_ws;             // [B][128][2][512]
  unsigned short* kfb = qfb + (size_t)1048576;             // [B][128][2][512]
  unsigned short* vfb = kfb + (size_t)1048576;             // [B][64][4][512]
  unsigned short* Wf  = vfb + (size_t)1048576;             // [12][32][64][8]

  prep_w<<<dim3(96), 256, 0, stream>>>(Wk, Wq, Wv, Wf);
  qkv_proj<<<dim3(1024), 256, 0, stream>>>(x, bk, bq, bv, Wf, kfb, qfb, vfb);
  attn_fwd<<<dim3(512), 512, 0, stream>>>(qfb, kfb, vfb, out);
}

// Round 9
// 50.357 us; speedup vs baseline: 1.7527x; 1.0092x over previous
//
#include <hip/hip_runtime.h>
#include <hip/hip_bf16.h>
#include <math.h>

#define BB 8
#define TT 2048
#define EE 1024
#define HH 64
// 1/sqrt(64) * log2(e): fold into q so scores are in exp2 domain
#define QSCALE 0.18033688011112042f

typedef __attribute__((ext_vector_type(8))) short short8;
typedef __attribute__((ext_vector_type(4))) float f32x4;
typedef __attribute__((ext_vector_type(4))) unsigned short us4;

__device__ inline unsigned short f2bf(float f) {
  union { __hip_bfloat16 h; unsigned short u; } cv;
  cv.h = __float2bfloat16(f);
  return cv.u;
}

// ---------- prep: fragment-ordered weights --------------------------------
// Wf[t][ks][lane][j], t = m*4+hb; h=(t&3)*16+(lane&15), e=ks*32+(lane>>4)*8+j
__global__ __launch_bounds__(256) void prep_w(
    const float* __restrict__ Wk, const float* __restrict__ Wq,
    const float* __restrict__ Wv, unsigned short* __restrict__ Wf) {
  const int idx = blockIdx.x * 256 + threadIdx.x;  // 12*32*64 = 24576
  const int lane = idx & 63, ks = (idx >> 6) & 31, t = idx >> 11;
  const int q = lane & 15, g = lane >> 4;
  const int m = t >> 2, h = (t & 3) * 16 + q;
  const float* W = (m == 0) ? Wk : (m == 1) ? Wq : Wv;
  const float sc = (m == 1) ? QSCALE : 1.f;
  const int e0 = ks * 32 + g * 8;
  unsigned short v[8];
  #pragma unroll
  for (int j = 0; j < 8; ++j) v[j] = f2bf(W[(e0 + j) * 64 + h] * sc);
  *(short8*)&Wf[(size_t)idx * 8] = *(short8*)v;
}

// ---------- QKV projection: 32 rows/block, B-frag reuse across 2 M-strips --
// 512 blocks x 4 waves; wave w owns N-tiles {3w,3w+1,3w+2} x strips {0,1}.
// Chunked double-buffered staging (256 cols/chunk). Fragment-packed outputs.
__global__ __launch_bounds__(256) void qkv_proj(
    const float* __restrict__ x,
    const float* __restrict__ bk, const float* __restrict__ bq,
    const float* __restrict__ bv, const unsigned short* __restrict__ Wf,
    unsigned short* __restrict__ kf, unsigned short* __restrict__ qf,
    unsigned short* __restrict__ vf) {
  __shared__ alignas(16) unsigned short xs[2][32][264];

  const int tid = threadIdx.x;
  const long row0 = (long)blockIdx.x * 32;
  const int w = tid >> 6, lane = tid & 63;
  const int q = lane & 15, g = lane >> 4;

  const float4* xg = (const float4*)&x[row0 * EE];  // 32 rows x 256 f4

  // stage chunk 0 (cols 0..255): 2048 f4, 8 per thread
  #pragma unroll
  for (int i = 0; i < 8; ++i) {
    const int flat = i * 256 + tid;
    const int rr = flat >> 6, c4 = flat & 63;
    const float4 xv = xg[rr * 256 + c4];
    us4 pk = {f2bf(xv.x), f2bf(xv.y), f2bf(xv.z), f2bf(xv.w)};
    *(us4*)&xs[0][rr][c4 * 4] = pk;
  }
  __syncthreads();

  const f32x4 z = {0.f, 0.f, 0.f, 0.f};
  f32x4 acc00 = z, acc01 = z, acc02 = z;   // strip 0 x tiles {3w,3w+1,3w+2}
  f32x4 acc10 = z, acc11 = z, acc12 = z;   // strip 1
  const unsigned short* wf0 = &Wf[(size_t)(3 * w) * 16384 + (size_t)lane * 8];

  float4 st[8];
  #pragma unroll
  for (int cc = 0; cc < 4; ++cc) {
    if (cc < 3) {  // issue next chunk's loads early; latency hides under MFMA
      #pragma unroll
      for (int i = 0; i < 8; ++i) {
        const int flat = i * 256 + tid;
        const int rr = flat >> 6, c4 = flat & 63;
        st[i] = xg[rr * 256 + (cc + 1) * 64 + c4];
      }
    }
    #pragma unroll
    for (int ksl = 0; ksl < 8; ++ksl) {
      const short8 a0 = *(const short8*)&xs[cc & 1][q][ksl * 32 + g * 8];
      const short8 a1 = *(const short8*)&xs[cc & 1][16 + q][ksl * 32 + g * 8];
      const int ks = cc * 8 + ksl;
      const short8 b0 = *(const short8*)&wf0[ks * 512];
      const short8 b1 = *(const short8*)&wf0[16384 + ks * 512];
      const short8 b2 = *(const short8*)&wf0[32768 + ks * 512];
      acc00 = __builtin_amdgcn_mfma_f32_16x16x32_bf16(a0, b0, acc00, 0, 0, 0);
      acc10 = __builtin_amdgcn_mfma_f32_16x16x32_bf16(a1, b0, acc10, 0, 0, 0);
      acc01 = __builtin_amdgcn_mfma_f32_16x16x32_bf16(a0, b1, acc01, 0, 0, 0);
      acc11 = __builtin_amdgcn_mfma_f32_16x16x32_bf16(a1, b1, acc11, 0, 0, 0);
      acc02 = __builtin_amdgcn_mfma_f32_16x16x32_bf16(a0, b2, acc02, 0, 0, 0);
      acc12 = __builtin_amdgcn_mfma_f32_16x16x32_bf16(a1, b2, acc12, 0, 0, 0);
    }
    if (cc < 3) {
      #pragma unroll
      for (int i = 0; i < 8; ++i) {
        const int flat = i * 256 + tid;
        const int rr = flat >> 6, c4 = flat & 63;
        us4 pk = {f2bf(st[i].x), f2bf(st[i].y), f2bf(st[i].z), f2bf(st[i].w)};
        *(us4*)&xs[(cc + 1) & 1][rr][c4 * 4] = pk;
      }
    }
    __syncthreads();
  }

  // epilogue: D[row=4g+r][col=q] per (strip, tile); fragment-packed stores
  const long bidx = row0 >> 11;
  const int tl0 = (int)(row0 & 2047);
  #pragma unroll
  for (int i = 0; i < 3; ++i) {
    const int tgl = 3 * w + i;
    const int mm = tgl >> 2, hb = tgl & 3;
    const int h = hb * 16 + q;
    const float bias = (mm == 0) ? bk[h] : (mm == 1) ? bq[h] * QSCALE : bv[h];
    #pragma unroll
    for (int stp = 0; stp < 2; ++stp) {
      const f32x4 a = (stp == 0) ? ((i == 0) ? acc00 : (i == 1) ? acc01 : acc02)
                                 : ((i == 0) ? acc10 : (i == 1) ? acc11 : acc12);
      #pragma unroll
      for (int r = 0; r < 4; ++r) {
        const int tl = tl0 + stp * 16 + 4 * g + r;
        const unsigned short ov = f2bf(a[r] + bias);
        if (mm == 2) {
          const size_t vidx = (size_t)bidx * 131072 + (size_t)(tl >> 5) * 2048 +
                              (size_t)(h >> 4) * 512 +
                              (size_t)((tl & 31) >> 3) * 128 +
                              (size_t)(h & 15) * 8 + (tl & 7);
          vf[vidx] = ov;
        } else {
          const size_t kqidx = (size_t)bidx * 131072 + (size_t)(tl >> 4) * 1024 +
                               (size_t)(h >> 5) * 512 +
                               (size_t)((h & 31) >> 3) * 128 +
                               (size_t)(tl & 15) * 8 + (h & 7);
          if (mm == 0) kf[kqidx] = ov; else qf[kqidx] = ov;
        }
      }
    }
  }
}

// ---------- flash attention: paired strips, proportional wave split --------
// S^T = mfma(K, Q): lane holds S^T[key=4g+r][q]; defer-max online softmax;
// O^T = mfma(V^T, P^T). All operand loads coalesced (fragment-packed).
#define BODY(KC0, KC1, KC2, KC3, KN0, KN1, KN2, KN3, tt, PREF) do {          \
    const unsigned short* vp_ = vfb + (size_t)(tt) * 2048;                   \
    const short8 V0 = *(const short8*)&vp_[0];                               \
    const short8 V1 = *(const short8*)&vp_[512];                             \
    const short8 V2 = *(const short8*)&vp_[1024];                            \
    const short8 V3 = *(const short8*)&vp_[1536];                            \
    if (PREF) {                                                              \
      const unsigned short* kp_ = kfb + (size_t)((tt) + stride) * 2048;      \
      KN0 = *(const short8*)&kp_[0];                                         \
      KN1 = *(const short8*)&kp_[512];                                       \
      KN2 = *(const short8*)&kp_[1024];                                      \
      KN3 = *(const short8*)&kp_[1536];                                      \
    }                                                                        \
    f32x4 sa = __builtin_amdgcn_mfma_f32_16x16x32_bf16(KC0, Qf0, z, 0,0,0);  \
    sa = __builtin_amdgcn_mfma_f32_16x16x32_bf16(KC1, Qf1, sa, 0,0,0);       \
    f32x4 sb = __builtin_amdgcn_mfma_f32_16x16x32_bf16(KC2, Qf0, z, 0,0,0);  \
    sb = __builtin_amdgcn_mfma_f32_16x16x32_bf16(KC3, Qf1, sb, 0,0,0);       \
    const int k0_ = (tt) * 32;                                               \
    if (k0_ + 31 > q0) {                                                     \
      _Pragma("unroll")                                                      \
      for (int r = 0; r < 4; ++r) {                                          \
        if (k0_ + 4 * g + r > qg) sa[r] = -INFINITY;                         \
        if (k0_ + 16 + 4 * g + r > qg) sb[r] = -INFINITY;                    \
      }                                                                      \
    }                                                                        \
    float pmax = fmaxf(fmaxf(fmaxf(sa[0], sa[1]), fmaxf(sa[2], sa[3])),      \
                       fmaxf(fmaxf(sb[0], sb[1]), fmaxf(sb[2], sb[3])));     \
    if (!__all(pmax <= m + 8.0f)) {                                          \
      float tmax = pmax;                                                     \
      tmax = fmaxf(tmax, __shfl_xor(tmax, 16));                              \
      tmax = fmaxf(tmax, __shfl_xor(tmax, 32));                              \
      const float nm = fmaxf(m, tmax);                                       \
      const float rs = __builtin_amdgcn_exp2f(m - nm);                       \
      l *= rs; o0 *= rs; o1 *= rs; o2 *= rs; o3 *= rs;                       \
      m = nm;                                                                \
    }                                                                        \
    float ps = 0.f;                                                          \
    _Pragma("unroll")                                                        \
    for (int r = 0; r < 4; ++r) {                                            \
      sa[r] = __builtin_amdgcn_exp2f(sa[r] - m); ps += sa[r];                \
      sb[r] = __builtin_amdgcn_exp2f(sb[r] - m); ps += sb[r];                \
    }                                                                        \
    l += ps;                                                                 \
    unsigned pw0, pw1, pw2, pw3;                                             \
    asm("v_cvt_pk_bf16_f32 %0, %1, %2" : "=v"(pw0) : "v"(sa[0]), "v"(sa[1]));\
    asm("v_cvt_pk_bf16_f32 %0, %1, %2" : "=v"(pw1) : "v"(sa[2]), "v"(sa[3]));\
    asm("v_cvt_pk_bf16_f32 %0, %1, %2" : "=v"(pw2) : "v"(sb[0]), "v"(sb[1]));\
    asm("v_cvt_pk_bf16_f32 %0, %1, %2" : "=v"(pw3) : "v"(sb[2]), "v"(sb[3]));\
    const int srcA = q + ((g & 1) << 5);                                     \
    const int srcB = srcA + 16;                                              \
    const unsigned r0a = __shfl((int)pw0, srcA);                             \
    const unsigned r1a = __shfl((int)pw1, srcA);                             \
    const unsigned r2a = __shfl((int)pw2, srcA);                             \
    const unsigned r3a = __shfl((int)pw3, srcA);                             \
    const unsigned r0b = __shfl((int)pw0, srcB);                             \
    const unsigned r1b = __shfl((int)pw1, srcB);                             \
    const unsigned r2b = __shfl((int)pw2, srcB);                             \
    const unsigned r3b = __shfl((int)pw3, srcB);                             \
    union { unsigned u[4]; short8 s; } pf_;                                  \
    const bool hi_ = (g >= 2);                                               \
    pf_.u[0] = hi_ ? r2a : r0a;                                              \
    pf_.u[1] = hi_ ? r3a : r1a;                                              \
    pf_.u[2] = hi_ ? r2b : r0b;                                              \
    pf_.u[3] = hi_ ? r3b : r1b;                                              \
    const short8 Pf = pf_.s;                                                 \
    o0 = __builtin_amdgcn_mfma_f32_16x16x32_bf16(V0, Pf, o0, 0,0,0);         \
    o1 = __builtin_amdgcn_mfma_f32_16x16x32_bf16(V1, Pf, o1, 0,0,0);         \
    o2 = __builtin_amdgcn_mfma_f32_16x16x32_bf16(V2, Pf, o2, 0,0,0);         \
    o3 = __builtin_amdgcn_mfma_f32_16x16x32_bf16(V3, Pf, o3, 0,0,0);         \
  } while (0)

__global__ __launch_bounds__(512) void attn_fwd(
    const unsigned short* __restrict__ qf, const unsigned short* __restrict__ kf,
    const unsigned short* __restrict__ vf, float* __restrict__ out) {
  __shared__ float accS[8][64][17];
  __shared__ float mlS[8][2][16];

  const int tid = threadIdx.x;
  const int w = tid >> 6, lane = tid & 63;
  const int q = lane & 15, g = lane >> 4;

  const int b = blockIdx.x & 7;
  const int p = blockIdx.x >> 3;           // pair 0..63
  const int s1 = 127 - p;
  const int nt0 = (p + 2) >> 1, nt1 = (129 - p) >> 1;   // nt0 + nt1 = 65
  int k = (8 * nt0 + 32) / 65;
  if (k < 1) k = 1;
  if (k > 7) k = 7;

  const bool onS0 = (w < k);
  const int s = onS0 ? p : s1;
  const int nt = onS0 ? nt0 : nt1;
  const int stride = onS0 ? k : (8 - k);
  int t = onS0 ? w : (w - k);

  const int q0 = s * 16;
  const int qg = q0 + q;

  const unsigned short* kfb = kf + (size_t)b * 131072 + (size_t)lane * 8;
  const unsigned short* vfb = vf + (size_t)b * 131072 + (size_t)lane * 8;
  const unsigned short* qfb = qf + (size_t)b * 131072 + (size_t)s * 1024 +
                              (size_t)lane * 8;
  const short8 Qf0 = *(const short8*)&qfb[0];
  const short8 Qf1 = *(const short8*)&qfb[512];

  const f32x4 z = {0.f, 0.f, 0.f, 0.f};
  float m = -3.0e38f, l = 0.f;
  f32x4 o0 = z, o1 = z, o2 = z, o3 = z;

  {
    short8 A0, A1, A2, A3, B0, B1, B2, B3;
    const unsigned short* kp0 = kfb + (size_t)t * 2048;
    A0 = *(const short8*)&kp0[0];
    A1 = *(const short8*)&kp0[512];
    A2 = *(const short8*)&kp0[1024];
    A3 = *(const short8*)&kp0[1536];
    for (;;) {
      bool pf = (t + stride) < nt;
      BODY(A0, A1, A2, A3, B0, B1, B2, B3, t, pf);
      if (!pf) break;
      t += stride;
      pf = (t + stride) < nt;
      BODY(B0, B1, B2, B3, A0, A1, A2, A3, t, pf);
      if (!pf) break;
      t += stride;
    }
  }

  // finalize per-wave state: l summed across g (2 shfl, once per kernel)
  float lq = l;
  lq += __shfl_xor(lq, 16);
  lq += __shfl_xor(lq, 32);
  #pragma unroll
  for (int hb = 0; hb < 4; ++hb) {
    const f32x4 a = (hb == 0) ? o0 : (hb == 1) ? o1 : (hb == 2) ? o2 : o3;
    #pragma unroll
    for (int r = 0; r < 4; ++r) accS[w][16 * hb + 4 * g + r][q] = a[r];
  }
  if (g == 0) { mlS[w][0][q] = m; mlS[w][1][q] = lq; }
  __syncthreads();

  // merge: tid<256 -> strip p (slots 0..k-1), tid>=256 -> strip 127-p (k..7)
  const int half = tid >> 8;
  const int sm = half ? s1 : p;
  const int lo = half ? k : 0, hi = half ? 8 : k;
  const int row = tid & 63, qq = (tid >> 6) & 3;
  const long obase = ((long)b * TT + sm * 16) * 64;
  #pragma unroll
  for (int kk = 0; kk < 4; ++kk) {
    const int qv = qq + 4 * kk;
    float M = -INFINITY;
    for (int i = lo; i < hi; ++i) M = fmaxf(M, mlS[i][0][qv]);
    float L = 0.f, acc = 0.f;
    for (int i = lo; i < hi; ++i) {
      const float fi = __builtin_amdgcn_exp2f(mlS[i][0][qv] - M);
      L += fi * mlS[i][1][qv];
      acc += fi * accS[i][row][qv];
    }
    out[obase + (long)qv * 64 + row] = acc / L;
  }
}

extern "C" void kernel_launch(void* const* d_in, const int* in_sizes, int n_in,
                              void* d_out, int out_size, void* d_ws, size_t ws_size,
                              hipStream_t stream) {
  const float* x  = (const float*)d_in[0];
  const float* Wk = (const float*)d_in[1];
  const float* bk = (const float*)d_in[2];
  const float* Wq = (const float*)d_in[3];
  const float* bq = (const float*)d_in[4];
  const float* Wv = (const float*)d_in[5];
  const float* bv = (const float*)d_in[6];
  float* out = (float*)d_out;

  unsigned short* qfb = (unsigned short*)d_ws;             // [B][128][2][512]
  unsigned short* kfb = qfb + (size_t)1048576;             // [B][128][2][512]
  unsigned short* vfb = kfb + (size_t)1048576;             // [B][64][4][512]
  unsigned short* Wf  = vfb + (size_t)1048576;             // [12][32][64][8]

  prep_w<<<dim3(96), 256, 0, stream>>>(Wk, Wq, Wv, Wf);
  qkv_proj<<<dim3(512), 256, 0, stream>>>(x, bk, bq, bv, Wf, kfb, qfb, vfb);
  attn_fwd<<<dim3(512), 512, 0, stream>>>(qfb, kfb, vfb, out);
}